// Round 13
// baseline (186.575 us; speedup 1.0000x reference)
//
#include <hip/hip_runtime.h>
#include <hip/hip_bf16.h>
#include <math.h>

// Problem constants (fixed by the reference)
#define B_SZ   4096
#define D      64
#define RPB    8192                 // rows per branch = 2*B
#define NCHUNK 8                    // 1024-col chunks per branch
#define TPW    16                   // 64-col tiles per chunk (per wave)
#define NPART  8                    // partials per row = NCHUNK
#define LN2    0.69314718055994531f
#define PRESCALE 2.6857914f         // sqrt(5 * log2(e)); X pre-scaled so Gram = base-2 logits
#define DEFER_THR 60.0f             // item max-defer threshold (terms <= 2^60, f32-safe)

typedef __attribute__((ext_vector_type(8))) short  bf16x8;
typedef __attribute__((ext_vector_type(4))) float  f32x4;

__device__ __forceinline__ float fexp2(float x) { return __builtin_amdgcn_exp2f(x); }

// Direct global->LDS copy, 16 B per lane, zero VGPR destination cost.
typedef const __attribute__((address_space(1))) unsigned int* gptr_t;
typedef __attribute__((address_space(3))) unsigned int* lptr_t;
__device__ __forceinline__ void stage16(const void* g, void* l) {
    __builtin_amdgcn_global_load_lds((gptr_t)g, (lptr_t)l, 16, 0, 0);
}

// ws layout:
//   Xbf  : 2*8192*64 bf16  = 2 MB   (pre-scaled by PRESCALE)
//   dots : 8192 float      = 32 KB  (v1_i . v2_i, unscaled fp32)
//   P    : 16384*8 float2  = 1 MB   (per-row per-chunk (m,s), base-2; user m=0)

// ---------------------------------------------------------------------------
// Gather + normalize + dots + bf16 pack. Also zeroes the output scalar
// (stream-ordered before merge_kernel's atomics).
__global__ __launch_bounds__(256) void gather_kernel(
    const int* __restrict__ u_idx, const int* __restrict__ i_idx,
    const float* __restrict__ u1e, const float* __restrict__ i1e,
    const float* __restrict__ u2e, const float* __restrict__ i2e,
    __hip_bfloat16* __restrict__ Xbf, float* __restrict__ dots,
    float* __restrict__ out)
{
    const int tid  = threadIdx.x;
    if (blockIdx.x == 0 && tid == 0) *out = 0.f;
    const int wave = tid >> 6, lane = tid & 63;
    const int g      = blockIdx.x * 4 + wave;   // 0..8191
    const int branch = g >> 12;
    const int i      = g & (B_SZ - 1);
    const int idx    = (branch == 0) ? u_idx[i] : i_idx[i];
    const float* s1  = (branch == 0) ? u1e : i1e;
    const float* s2  = (branch == 0) ? u2e : i2e;

    float v1 = s1[(size_t)idx * D + lane];
    float v2 = s2[(size_t)idx * D + lane];
    if (branch == 0) {
        float a = v1 * v1, b = v2 * v2;
        #pragma unroll
        for (int o = 32; o > 0; o >>= 1) {
            a += __shfl_xor(a, o, 64);
            b += __shfl_xor(b, o, 64);
        }
        v1 *= rsqrtf(a);
        v2 *= rsqrtf(b);
    }
    float p = v1 * v2;
    #pragma unroll
    for (int o = 32; o > 0; o >>= 1) p += __shfl_xor(p, o, 64);
    if (lane == 0) dots[g] = p;

    const size_t row1 = (size_t)branch * RPB + i;
    Xbf[row1 * D + lane]          = __float2bfloat16(v1 * PRESCALE);
    Xbf[(row1 + B_SZ) * D + lane] = __float2bfloat16(v2 * PRESCALE);
}

// ---------------------------------------------------------------------------
// BARRIER-FREE MFMA Gram + per-lane online logsumexp (base-2).
// R13: 1-wave blocks; each wave owns a PRIVATE 2x8KB LDS double buffer and a
// 64-row x 1024-col output strip (16 tiles of 64 cols; per-tile work is R6's
// per-wave work verbatim). Per tile: ds_read(t) [compiler's auto vmcnt(0)
// waits only on tile t's stage, issued one full MFMA+epilogue ago -> ~free]
// -> sched_barrier(0) [keeps the next stage below the reads] -> stage(t+1)
// -> 32-MFMA burst -> exp2 epilogue (hides t+1's L2 latency). NO
// __syncthreads: waves free-run at independent phases (one wave's MFMA
// overlaps another's epilogue on the same SIMD).
// XOR swizzle (byte ^= (row&7)<<4) on the GLOBAL SOURCE address (LDS dest
// linear; verified R6); ds_read applies the same XOR.
// IS_USER=1: logits bounded (|y|<=7.3) -> plain exp2-sum.
// IS_USER=0: deferred-max (THR=60; passed R9/R11/R12, absmax 0).
template<int IS_USER>
__device__ __forceinline__ void gram_body(
    const __hip_bfloat16* __restrict__ Xb, float2* __restrict__ P,
    const int rowg, const int chunk, char* sm)
{
    const int lane = threadIdx.x & 63;
    const int quad = lane >> 4, tx = lane & 15;
    const int r0   = rowg * 64;

    // Stage addressing: dest LDS byte L = k*1024 + lane*16 (linear, private).
    // Source swizzle-adjusted: row = L>>7 = k*8 + (lane>>3),
    // srccol = (L&127) ^ ((row&7)<<4).
    const int srow_b = lane >> 3;                                // + k*8
    const int scb    = ((lane & 7) * 16) ^ ((lane >> 3) << 4);
    const char* Xbytes = (const char*)Xb;

    // Prologue: stage tile 0 (64 rows x 128 B = 8 KB) into buffer 0.
    {
        const char* src = Xbytes + (size_t)(chunk * TPW) * 8192;
        #pragma unroll
        for (int k = 0; k < 8; ++k)
            stage16(src + (srow_b + k * 8) * 128 + scb, sm + k * 1024 + lane * 16);
    }

    // A fragments hoisted to registers, straight from global (K=64 fits).
    bf16x8 afr[4][2];
    const __hip_bfloat16* Ap = Xb + (size_t)(r0 + tx) * D + quad * 8;
    #pragma unroll
    for (int mt = 0; mt < 4; ++mt)
        #pragma unroll
        for (int ks = 0; ks < 2; ++ks)
            afr[mt][ks] = *(const bf16x8*)(Ap + mt * 16 * D + ks * 32);

    float m_run[16], s_run[16];
    #pragma unroll
    for (int r = 0; r < 16; ++r) { m_run[r] = -INFINITY; s_run[r] = 0.f; }

    const int lrq = quad * 4;              // + mt*16 + rr = strip-local row

    // ds_read addressing (swizzled): row = nt*16 + tx, row&7 = tx&7.
    const int rbase = tx * 128;            // + nt*2048
    const int key   = (tx & 7) << 4;
    const int cb0   = (quad * 16) ^ key;
    const int cb1   = (64 + quad * 16) ^ key;

    #pragma unroll 1
    for (int t = 0; t < TPW; ++t) {
        const int ct  = chunk * TPW + t;       // global 64-col tile, 0..127
        const int cur = (t & 1) << 13;

        // B fragments from LDS (compiler inserts the vmcnt wait for tile t's
        // stage here -- the only outstanding loads, issued one iteration ago).
        bf16x8 b0[4], b1[4];
        #pragma unroll
        for (int nt = 0; nt < 4; ++nt) {
            b0[nt] = *(const bf16x8*)(sm + cur + rbase + nt * 2048 + cb0);
            b1[nt] = *(const bf16x8*)(sm + cur + rbase + nt * 2048 + cb1);
        }
        __builtin_amdgcn_sched_barrier(0);     // stage stays BELOW the reads

        // Stage tile t+1 into the other private buffer (WAR-safe: its dest
        // buffer was last read one iteration ago by this same wave).
        if (t + 1 < TPW) {
            const char* src = Xbytes + (size_t)(ct + 1) * 8192;
            char* dst = sm + (((t + 1) & 1) << 13);
            #pragma unroll
            for (int k = 0; k < 8; ++k)
                stage16(src + (srow_b + k * 8) * 128 + scb, dst + k * 1024 + lane * 16);
        }

        f32x4 acc[4][4];
        const f32x4 z = {0.f, 0.f, 0.f, 0.f};
        #pragma unroll
        for (int nt = 0; nt < 4; ++nt)
            #pragma unroll
            for (int mt = 0; mt < 4; ++mt)
                acc[mt][nt] = __builtin_amdgcn_mfma_f32_16x16x32_bf16(afr[mt][0], b0[nt], z, 0, 0, 0);
        #pragma unroll
        for (int nt = 0; nt < 4; ++nt)
            #pragma unroll
            for (int mt = 0; mt < 4; ++mt)
                acc[mt][nt] = __builtin_amdgcn_mfma_f32_16x16x32_bf16(afr[mt][1], b1[nt], acc[mt][nt], 0, 0, 0);

        const bool diag = (ct == rowg);
        #pragma unroll
        for (int mt = 0; mt < 4; ++mt) {
            #pragma unroll
            for (int rr = 0; rr < 4; ++rr) {
                float y0 = acc[mt][0][rr], y1 = acc[mt][1][rr],
                      y2 = acc[mt][2][rr], y3 = acc[mt][3][rr];
                if (diag) {                  // acc already = base-2 logits (pre-scaled X)
                    const int dr = lrq + mt * 16 + rr - tx;
                    if (dr == 0)  y0 = -INFINITY;
                    if (dr == 16) y1 = -INFINITY;
                    if (dr == 32) y2 = -INFINITY;
                    if (dr == 48) y3 = -INFINITY;
                }
                const int r = mt * 4 + rr;
                if (IS_USER) {
                    s_run[r] += fexp2(y0) + fexp2(y1) + fexp2(y2) + fexp2(y3);
                } else {
                    // Deferred max (R9/R11/R12-proven): rescale only on jump > THR.
                    float mx = fmaxf(fmaxf(y0, y1), fmaxf(y2, y3));
                    if (__builtin_expect(mx > m_run[r] + DEFER_THR, 0)) {
                        s_run[r] *= fexp2(m_run[r] - mx);   // -inf first -> s stays 0
                        m_run[r] = mx;
                    }
                    const float m = m_run[r];
                    s_run[r] += fexp2(y0 - m) + fexp2(y1 - m)
                              + fexp2(y2 - m) + fexp2(y3 - m);
                }
            }
        }
    }

    // Once per strip: merge across the 16 tx lanes, write the (row, chunk)
    // partial. (lse = m + log2(s) invariant holds for any finite m.)
    #pragma unroll
    for (int r = 0; r < 16; ++r) {
        float m = IS_USER ? 0.f : m_run[r];
        float s = s_run[r];
        #pragma unroll
        for (int o = 1; o < 16; o <<= 1) {
            if (IS_USER) {
                s += __shfl_xor(s, o, 64);
            } else {
                float om = __shfl_xor(m, o, 64);
                float os = __shfl_xor(s, o, 64);
                float M  = fmaxf(m, om);
                s = s * fexp2(m - M) + os * fexp2(om - M);
                m = M;
            }
        }
        if (tx == 0) {
            const int grow = r0 + (r >> 2) * 16 + quad * 4 + (r & 3);
            P[(size_t)grow * NPART + chunk] = make_float2(m, s);
        }
    }
}

__global__ __launch_bounds__(64) void gram_lse_fused(
    const __hip_bfloat16* __restrict__ Xb0, float2* __restrict__ P0)
{
    __shared__ __align__(16) char sm[16384];     // private 2 x 8KB B buffers
    const int bid    = blockIdx.x;               // 0..2047
    const int branch = bid & 1;                  // interleaved for CU balance
    const int rest   = bid >> 1;                 // 0..1023
    const int rowg   = rest & 127;               // 64-row group
    const int chunk  = rest >> 7;                // 0..7
    const __hip_bfloat16* Xb = Xb0 + (size_t)branch * RPB * D;
    float2* P = P0 + (size_t)branch * RPB * NPART;
    if (branch == 0) gram_body<1>(Xb, P, rowg, chunk, sm);
    else             gram_body<0>(Xb, P, rowg, chunk, sm);
}

// ---------------------------------------------------------------------------
// Merge the 8 per-row partials -> lse -> reduce; fold in the positive-pair
// correction from dots[]. 128 blocks x 4 iters (8 rows per wave per iter).
__global__ __launch_bounds__(256) void merge_kernel(
    const float2* __restrict__ P, const float* __restrict__ dots,
    float* __restrict__ out)
{
    __shared__ float red[4];
    const int tid  = threadIdx.x;
    const int wave = tid >> 6, lane = tid & 63;

    float vsum = 0.f;
    #pragma unroll
    for (int it = 0; it < 4; ++it) {
        const int row = blockIdx.x * 128 + it * 32 + wave * 8 + (lane >> 3);
        const int c   = lane & 7;

        float2 p = P[(size_t)row * NPART + c];
        float m = p.x, s = p.y;
        #pragma unroll
        for (int o = 1; o < 8; o <<= 1) {          // online merge across 8 lanes
            float om = __shfl_xor(m, o, 64);
            float os = __shfl_xor(s, o, 64);
            float M  = fmaxf(m, om);
            s = s * fexp2(m - M) + os * fexp2(om - M);
            m = M;
        }

        if ((lane & 7) == 0)
            vsum += LN2 * (m + log2f(s)) * (1.0f / (float)RPB);   // lse_row / (2B)
    }

    // positive-pair correction: 64 dots per block
    if (tid < 64)
        vsum -= dots[blockIdx.x * 64 + tid] * (5.0f / (float)B_SZ);

    float v = vsum;
    #pragma unroll
    for (int o = 32; o > 0; o >>= 1) v += __shfl_xor(v, o, 64);
    if (lane == 0) red[wave] = v;
    __syncthreads();
    if (tid == 0)
        atomicAdd(out, red[0] + red[1] + red[2] + red[3]);
}

// ---------------------------------------------------------------------------
extern "C" void kernel_launch(void* const* d_in, const int* in_sizes, int n_in,
                              void* d_out, int out_size, void* d_ws, size_t ws_size,
                              hipStream_t stream) {
    const int*   u_idx = (const int*)d_in[0];
    const int*   i_idx = (const int*)d_in[1];
    const float* u1e   = (const float*)d_in[2];
    const float* i1e   = (const float*)d_in[3];
    const float* u2e   = (const float*)d_in[4];
    const float* i2e   = (const float*)d_in[5];
    float* out = (float*)d_out;

    __hip_bfloat16* Xbf = (__hip_bfloat16*)d_ws;                  // 2 MB
    float*  dots = (float*)((char*)d_ws + 2 * RPB * D * 2);       // 32 KB
    float2* P    = (float2*)((char*)dots + RPB * sizeof(float));  // 1 MB

    gather_kernel<<<dim3(2048), dim3(256), 0, stream>>>(
        u_idx, i_idx, u1e, i1e, u2e, i2e, Xbf, dots, out);
    // 2048 one-wave blocks = 8/CU, all co-resident, barrier-free
    gram_lse_fused<<<dim3(2048), dim3(64), 0, stream>>>(Xbf, P);
    merge_kernel<<<dim3(128), dim3(256), 0, stream>>>(P, dots, out);
}

// Round 14
// 176.428 us; speedup vs baseline: 1.0575x; 1.0575x over previous
//
#include <hip/hip_runtime.h>
#include <hip/hip_bf16.h>
#include <math.h>

// Problem constants (fixed by the reference)
#define B_SZ   4096
#define D      64
#define RPB    8192                 // rows per branch = 2*B
#define NCHUNK 8                    // column chunks
#define TPC    8                    // 128-col tiles per chunk
#define NPART  16                   // partials per row = NCHUNK * 2 (wn halves)
#define LN2    0.69314718055994531f
#define PRESCALE 2.6857914f         // sqrt(5 * log2(e)); X pre-scaled so Gram = base-2 logits

typedef __attribute__((ext_vector_type(8))) short  bf16x8;
typedef __attribute__((ext_vector_type(4))) float  f32x4;

__device__ __forceinline__ float fexp2(float x) { return __builtin_amdgcn_exp2f(x); }

// Direct global->LDS copy, 16 B per lane, zero VGPR destination cost.
typedef const __attribute__((address_space(1))) unsigned int* gptr_t;
typedef __attribute__((address_space(3))) unsigned int* lptr_t;
__device__ __forceinline__ void stage16(const void* g, void* l) {
    __builtin_amdgcn_global_load_lds((gptr_t)g, (lptr_t)l, 16, 0, 0);
}

// ws layout:
//   Xbf  : 2*8192*64 bf16  = 2 MB   (pre-scaled by PRESCALE)
//   dots : 8192 float      = 32 KB  (v1_i . v2_i, unscaled fp32)
//   P    : 16384*16 float2 = 2 MB   (per-row per-(chunk,wn) (m,s), base-2; user m=0)

// ---------------------------------------------------------------------------
// Gather + normalize + dots + bf16 pack. Also zeroes the output scalar
// (stream-ordered before merge_kernel's atomics).
__global__ __launch_bounds__(256) void gather_kernel(
    const int* __restrict__ u_idx, const int* __restrict__ i_idx,
    const float* __restrict__ u1e, const float* __restrict__ i1e,
    const float* __restrict__ u2e, const float* __restrict__ i2e,
    __hip_bfloat16* __restrict__ Xbf, float* __restrict__ dots,
    float* __restrict__ out)
{
    const int tid  = threadIdx.x;
    if (blockIdx.x == 0 && tid == 0) *out = 0.f;
    const int wave = tid >> 6, lane = tid & 63;
    const int g      = blockIdx.x * 4 + wave;   // 0..8191
    const int branch = g >> 12;
    const int i      = g & (B_SZ - 1);
    const int idx    = (branch == 0) ? u_idx[i] : i_idx[i];
    const float* s1  = (branch == 0) ? u1e : i1e;
    const float* s2  = (branch == 0) ? u2e : i2e;

    float v1 = s1[(size_t)idx * D + lane];
    float v2 = s2[(size_t)idx * D + lane];
    if (branch == 0) {
        float a = v1 * v1, b = v2 * v2;
        #pragma unroll
        for (int o = 32; o > 0; o >>= 1) {
            a += __shfl_xor(a, o, 64);
            b += __shfl_xor(b, o, 64);
        }
        v1 *= rsqrtf(a);
        v2 *= rsqrtf(b);
    }
    float p = v1 * v2;
    #pragma unroll
    for (int o = 32; o > 0; o >>= 1) p += __shfl_xor(p, o, 64);
    if (lane == 0) dots[g] = p;

    const size_t row1 = (size_t)branch * RPB + i;
    Xbf[row1 * D + lane]          = __float2bfloat16(v1 * PRESCALE);
    Xbf[(row1 + B_SZ) * D + lane] = __float2bfloat16(v2 * PRESCALE);
}

// ---------------------------------------------------------------------------
// MFMA Gram + per-lane online logsumexp (base-2). Per-wave math, staging
// volume, swizzle, and epilogue are BYTE-IDENTICAL to R6 (best: 49.8us).
// R14 changes ONLY the workgroup decomposition: 128-thread blocks (2 waves,
// wm=0/1) own ONE wn-half -> private 64-row B panel, 2x8KB double buffer
// (16 KB LDS/block). Occupancy probe: every 4-wave config pinned at ~19-20%
// residency (even LDS=0); if workgroup granularity was the limiter, 6
// blocks/CU x 2 waves = 12 waves/CU now fit. Barrier scope halves (2 waves).
// Total staged bytes unchanged: each wn-block stages its own 64 rows.
// IS_USER=1: logits bounded (|y|<=7.3) -> no max tracking, plain exp2-sum.
template<int IS_USER>
__device__ __forceinline__ void gram_body(
    const __hip_bfloat16* __restrict__ Xb, float2* __restrict__ P,
    const int bx, const int chunk, const int wn, char* sm)
{
    const int tid  = threadIdx.x;
    const int r0   = bx * 128;
    const int wm   = tid >> 6;           // wave 0/1
    const int lane = tid & 63;
    const int quad = lane >> 4, tx = lane & 15;

    // Stage addressing: dest LDS byte L = k*2048 + wm*1024 + lane*16 (linear).
    // Source swizzle-adjusted: row = L>>7 = k*16 + wm*8 + (lane>>3),
    // srccol = (L&127) ^ ((row&7)<<4); row&7 = lane>>3.
    const int srow_b = wm * 8 + (lane >> 3);                     // + k*16
    const int scb    = ((lane & 7) * 16) ^ ((lane >> 3) << 4);
    const char* Xbytes = (const char*)Xb;   // B rows: ct*128 + wn*64 + row

    // Prologue: stage tile 0's half (64 rows x 128 B = 8 KB) into buffer 0.
    {
        const char* src = Xbytes + ((size_t)(chunk * TPC) * 128 + wn * 64) * 128;
        #pragma unroll
        for (int k = 0; k < 4; ++k)
            stage16(src + (srow_b + k * 16) * 128 + scb,
                    sm + k * 2048 + wm * 1024);
    }

    // A fragments hoisted to registers, straight from global (K=64 fits).
    bf16x8 afr[4][2];
    const __hip_bfloat16* Ap = Xb + (size_t)(r0 + wm * 64 + tx) * D + quad * 8;
    #pragma unroll
    for (int mt = 0; mt < 4; ++mt)
        #pragma unroll
        for (int ks = 0; ks < 2; ++ks)
            afr[mt][ks] = *(const bf16x8*)(Ap + mt * 16 * D + ks * 32);

    float m_run[16], s_run[16];
    #pragma unroll
    for (int r = 0; r < 16; ++r) { m_run[r] = -INFINITY; s_run[r] = 0.f; }

    const int lrq  = wm * 64 + quad * 4;   // + mt*16 + rr = block-local row
    const int lcol = wn * 64 + tx;         // + nt*16      = block-local col

    // ds_read addressing (swizzled): half-row = nt*16 + tx, row&7 = tx&7.
    const int rbase = tx * 128;            // + nt*2048
    const int key   = (tx & 7) << 4;
    const int cb0   = (quad * 16) ^ key;
    const int cb1   = (64 + quad * 16) ^ key;

    __syncthreads();   // tile 0 staged (compiler drains vmcnt before barrier)

    #pragma unroll 1
    for (int t = 0; t < TPC; ++t) {
        const int ct  = chunk * TPC + t;
        const int cur = (t & 1) << 13;

        // Stage tile t+1's half into the other buffer (WAR-safe: that buffer
        // was read at t-1, before the barrier ending t-1).
        if (t + 1 < TPC) {
            const char* src = Xbytes + ((size_t)(ct + 1) * 128 + wn * 64) * 128;
            char* dst = sm + (((t + 1) & 1) << 13) + wm * 1024;
            #pragma unroll
            for (int k = 0; k < 4; ++k)
                stage16(src + (srow_b + k * 16) * 128 + scb, dst + k * 2048);
        }

        // B fragments from LDS (swizzled addresses).
        bf16x8 b0[4], b1[4];
        #pragma unroll
        for (int nt = 0; nt < 4; ++nt) {
            b0[nt] = *(const bf16x8*)(sm + cur + rbase + nt * 2048 + cb0);
            b1[nt] = *(const bf16x8*)(sm + cur + rbase + nt * 2048 + cb1);
        }

        f32x4 acc[4][4];
        const f32x4 z = {0.f, 0.f, 0.f, 0.f};
        #pragma unroll
        for (int nt = 0; nt < 4; ++nt)
            #pragma unroll
            for (int mt = 0; mt < 4; ++mt)
                acc[mt][nt] = __builtin_amdgcn_mfma_f32_16x16x32_bf16(afr[mt][0], b0[nt], z, 0, 0, 0);
        #pragma unroll
        for (int nt = 0; nt < 4; ++nt)
            #pragma unroll
            for (int mt = 0; mt < 4; ++mt)
                acc[mt][nt] = __builtin_amdgcn_mfma_f32_16x16x32_bf16(afr[mt][1], b1[nt], acc[mt][nt], 0, 0, 0);

        const bool diag = (ct == bx);
        #pragma unroll
        for (int mt = 0; mt < 4; ++mt) {
            #pragma unroll
            for (int rr = 0; rr < 4; ++rr) {
                float y0 = acc[mt][0][rr], y1 = acc[mt][1][rr],
                      y2 = acc[mt][2][rr], y3 = acc[mt][3][rr];
                if (diag) {                  // acc already = base-2 logits (pre-scaled X)
                    const int dr = lrq + mt * 16 + rr - lcol;
                    if (dr == 0)  y0 = -INFINITY;
                    if (dr == 16) y1 = -INFINITY;
                    if (dr == 32) y2 = -INFINITY;
                    if (dr == 48) y3 = -INFINITY;
                }
                const int r = mt * 4 + rr;
                if (IS_USER) {
                    s_run[r] += fexp2(y0) + fexp2(y1) + fexp2(y2) + fexp2(y3);
                } else {
                    float mx   = fmaxf(fmaxf(y0, y1), fmaxf(y2, y3));
                    float newm = fmaxf(m_run[r], mx);
                    s_run[r] = s_run[r] * fexp2(m_run[r] - newm)
                             + fexp2(y0 - newm) + fexp2(y1 - newm)
                             + fexp2(y2 - newm) + fexp2(y3 - newm);
                    m_run[r] = newm;
                }
            }
        }

        // End-of-tile barrier: drains this wave's stage loads (vmcnt(0)
        // before s_barrier) and aligns the 2 waves' buffer phases.
        __syncthreads();
    }

    // Once per chunk: merge across the 16 tx lanes of THIS wave, write the
    // (row, chunk, wn) partial to its own slot.
    #pragma unroll
    for (int r = 0; r < 16; ++r) {
        float m = IS_USER ? 0.f : m_run[r];
        float s = s_run[r];
        #pragma unroll
        for (int o = 1; o < 16; o <<= 1) {
            if (IS_USER) {
                s += __shfl_xor(s, o, 64);
            } else {
                float om = __shfl_xor(m, o, 64);
                float os = __shfl_xor(s, o, 64);
                float M  = fmaxf(m, om);
                s = s * fexp2(m - M) + os * fexp2(om - M);
                m = M;
            }
        }
        if (tx == 0) {
            const int grow = r0 + wm * 64 + (r >> 2) * 16 + quad * 4 + (r & 3);
            P[(size_t)grow * NPART + chunk * 2 + wn] = make_float2(m, s);
        }
    }
}

__global__ __launch_bounds__(128, 3) void gram_lse_fused(
    const __hip_bfloat16* __restrict__ Xb0, float2* __restrict__ P0)
{
    __shared__ __align__(16) char sm[16384];     // 2 x 8KB private B-half buffers
    const int bid    = blockIdx.x;               // 0..2047
    const int branch = bid & 1;                  // interleaved for CU balance
    const int wn     = (bid >> 1) & 1;
    const int bx     = (bid >> 2) & 63;
    const int chunk  = bid >> 8;                 // 0..7
    const __hip_bfloat16* Xb = Xb0 + (size_t)branch * RPB * D;
    float2* P = P0 + (size_t)branch * RPB * NPART;
    if (branch == 0) gram_body<1>(Xb, P, bx, chunk, wn, sm);
    else             gram_body<0>(Xb, P, bx, chunk, wn, sm);
}

// ---------------------------------------------------------------------------
// Merge the 16 per-row partials -> lse -> reduce; fold in the positive-pair
// correction from dots[]. 128 blocks x 8-deep grid-stride.
__global__ __launch_bounds__(256) void merge_kernel(
    const float2* __restrict__ P, const float* __restrict__ dots,
    float* __restrict__ out)
{
    __shared__ float red[4];
    const int tid  = threadIdx.x;
    const int wave = tid >> 6, lane = tid & 63;

    float vsum = 0.f;
    #pragma unroll
    for (int k = 0; k < 8; ++k) {
        const int vb  = blockIdx.x * 8 + k;        // 0..1023
        const int gw  = vb * 4 + wave;             // 0..4095
        const int row = gw * 4 + (lane >> 4);      // 0..16383
        const int c   = lane & 15;

        float2 p = P[(size_t)row * NPART + c];
        float m = p.x, s = p.y;
        #pragma unroll
        for (int o = 1; o < 16; o <<= 1) {         // online merge across 16 lanes
            float om = __shfl_xor(m, o, 64);
            float os = __shfl_xor(s, o, 64);
            float M  = fmaxf(m, om);
            s = s * fexp2(m - M) + os * fexp2(om - M);
            m = M;
        }

        if ((lane & 15) == 0)
            vsum += LN2 * (m + log2f(s)) * (1.0f / (float)RPB);   // lse_row / (2B)
        if (tid < 8)                                              // positive-pair correction
            vsum -= dots[vb * 8 + tid] * (5.0f / (float)B_SZ);
    }

    float v = vsum;
    #pragma unroll
    for (int o = 32; o > 0; o >>= 1) v += __shfl_xor(v, o, 64);
    if (lane == 0) red[wave] = v;
    __syncthreads();
    if (tid == 0)
        atomicAdd(out, red[0] + red[1] + red[2] + red[3]);
}

// ---------------------------------------------------------------------------
extern "C" void kernel_launch(void* const* d_in, const int* in_sizes, int n_in,
                              void* d_out, int out_size, void* d_ws, size_t ws_size,
                              hipStream_t stream) {
    const int*   u_idx = (const int*)d_in[0];
    const int*   i_idx = (const int*)d_in[1];
    const float* u1e   = (const float*)d_in[2];
    const float* i1e   = (const float*)d_in[3];
    const float* u2e   = (const float*)d_in[4];
    const float* i2e   = (const float*)d_in[5];
    float* out = (float*)d_out;

    __hip_bfloat16* Xbf = (__hip_bfloat16*)d_ws;                  // 2 MB
    float*  dots = (float*)((char*)d_ws + 2 * RPB * D * 2);       // 32 KB
    float2* P    = (float2*)((char*)dots + RPB * sizeof(float));  // 2 MB

    gather_kernel<<<dim3(2048), dim3(256), 0, stream>>>(
        u_idx, i_idx, u1e, i1e, u2e, i2e, Xbf, dots, out);
    // 2048 two-wave blocks (one wn-half each); same total work as R6
    gram_lse_fused<<<dim3(2048), dim3(128), 0, stream>>>(Xbf, P);
    merge_kernel<<<dim3(128), dim3(256), 0, stream>>>(P, dots, out);
}